// Round 8
// baseline (207.267 us; speedup 1.0000x reference)
//
#include <hip/hip_runtime.h>
#include <stdint.h>

#define S 4096
#define E 1024
#define NH 16
#define HD 64
#define WSZ 512

typedef _Float16 f16x8 __attribute__((ext_vector_type(8)));
typedef _Float16 f16x4 __attribute__((ext_vector_type(4)));
typedef float f32x4 __attribute__((ext_vector_type(4)));
typedef unsigned short u16;
typedef unsigned int u32;

__device__ __forceinline__ u16 f2h_bits(float f) {
    union { _Float16 h; u16 u; } cv; cv.h = (_Float16)f; return cv.u;
}

__device__ __forceinline__ void gld16(const u16* g, u16* l) {
    __builtin_amdgcn_global_load_lds((const __attribute__((address_space(1))) void*)g,
                                     (__attribute__((address_space(3))) void*)l, 16, 0, 0);
}

// ---------------- fused fp32->fp16 converts (5 segments, 1 launch) ----------------
struct CvtArgs {
    const float* s[5];
    u16* d[5];
    int n[5];
};
__global__ void cvt5(CvtArgs a) {
    int seg = blockIdx.y;
    const float* __restrict__ s = a.s[seg];
    u16* __restrict__ d = a.d[seg];
    int n = a.n[seg];
    for (int i = (blockIdx.x * 256 + threadIdx.x) * 4; i < n; i += gridDim.x * 1024) {
        float4 f = *(const float4*)&s[i];
        uint2 o;
        o.x = (u32)f2h_bits(f.x) | ((u32)f2h_bits(f.y) << 16);
        o.y = (u32)f2h_bits(f.z) | ((u32)f2h_bits(f.w) << 16);
        *(uint2*)&d[i] = o;
    }
}

// ---------------- QKV bt-GEMM: 128x128 tile, BK=64 (split-half LDS, 64B row stride).
// n<2048 -> f16 QK (stride 2048); n>=2048 -> V^T f16 OutVT[n-2048][4096]. ----------------
__global__ __launch_bounds__(256) void gemm_qkv(
    const u16* __restrict__ A, const u16* __restrict__ B,
    u16* __restrict__ OutQK, u16* __restrict__ OutVT,
    const float* __restrict__ b0, const float* __restrict__ b1, const float* __restrict__ b2,
    int K) {
    __shared__ __align__(16) u16 As[2 * 128 * 32];   // [khalf][row][32]
    __shared__ __align__(16) u16 Bs[2 * 128 * 32];
    const int tid = threadIdx.x;
    const int wid = tid >> 6, lid = tid & 63, quad = lid >> 4, l16 = lid & 15;
    const int wm = wid >> 1, wn = wid & 1;
    const int bm0 = blockIdx.x * 128, bn0 = blockIdx.y * 128;

    f32x4 acc[4][4] = {};
    const int srow = tid >> 2, scol = (tid & 3) * 8;   // lane-linear LDS dest per call

    for (int k0 = 0; k0 < K; k0 += 64) {
        __syncthreads();
#pragma unroll
        for (int half = 0; half < 2; ++half)
#pragma unroll
            for (int rep = 0; rep < 2; ++rep) {
                gld16(&A[(size_t)(bm0 + rep * 64 + srow) * K + k0 + half * 32 + scol],
                      &As[half * 4096 + rep * 2048 + tid * 8]);
                gld16(&B[(size_t)(bn0 + rep * 64 + srow) * K + k0 + half * 32 + scol],
                      &Bs[half * 4096 + rep * 2048 + tid * 8]);
            }
        __syncthreads();
#pragma unroll
        for (int kk = 0; kk < 2; ++kk) {
            f16x8 af[4], bf[4];
#pragma unroll
            for (int i = 0; i < 4; ++i) af[i] = *(const f16x8*)&As[kk * 4096 + (wm * 64 + i * 16 + l16) * 32 + quad * 8];
#pragma unroll
            for (int j = 0; j < 4; ++j) bf[j] = *(const f16x8*)&Bs[kk * 4096 + (wn * 64 + j * 16 + l16) * 32 + quad * 8];
#pragma unroll
            for (int i = 0; i < 4; ++i)
#pragma unroll
                for (int j = 0; j < 4; ++j)
                    acc[i][j] = __builtin_amdgcn_mfma_f32_16x16x32_f16(af[i], bf[j], acc[i][j], 0, 0, 0);
        }
    }

    const bool isV = (bn0 >= 2048);   // block-uniform
#pragma unroll
    for (int j = 0; j < 4; ++j) {
        int n = bn0 + wn * 64 + j * 16 + l16;
        float bias = (n < 1024) ? b0[n] : (n < 2048 ? b1[n - 1024] : b2[n - 2048]);
#pragma unroll
        for (int i = 0; i < 4; ++i) {
            int m0 = bm0 + wm * 64 + i * 16 + quad * 4;
            if (!isV) {
#pragma unroll
                for (int r = 0; r < 4; ++r)
                    OutQK[(size_t)(m0 + r) * 2048 + n] = f2h_bits(acc[i][j][r] + bias);
            } else {
                u16 h0 = f2h_bits(acc[i][j][0] + bias);
                u16 h1 = f2h_bits(acc[i][j][1] + bias);
                u16 h2 = f2h_bits(acc[i][j][2] + bias);
                u16 h3 = f2h_bits(acc[i][j][3] + bias);
                uint2 pk;
                pk.x = (u32)h0 | ((u32)h1 << 16);
                pk.y = (u32)h2 | ((u32)h3 << 16);
                *(uint2*)&OutVT[(size_t)(n - 2048) * 4096 + m0] = pk;
            }
        }
    }
}

// ---------------- final proj bt-GEMM: 128(M)x64(N) tile, BK=64, f32 out + bias ----------------
__global__ __launch_bounds__(256) void gemm_n64(
    const u16* __restrict__ A, const u16* __restrict__ B, float* __restrict__ OutF,
    const float* __restrict__ bias, int N, int K) {
    __shared__ __align__(16) u16 As[2 * 128 * 32];
    __shared__ __align__(16) u16 Bs[2 * 64 * 32];
    const int tid = threadIdx.x;
    const int wid = tid >> 6, lid = tid & 63, quad = lid >> 4, l16 = lid & 15;
    const int bm0 = blockIdx.x * 128, bn0 = blockIdx.y * 64;

    f32x4 acc[2][4] = {};
    const int srow = tid >> 2, scol = (tid & 3) * 8;

    for (int k0 = 0; k0 < K; k0 += 64) {
        __syncthreads();
#pragma unroll
        for (int half = 0; half < 2; ++half) {
#pragma unroll
            for (int rep = 0; rep < 2; ++rep)
                gld16(&A[(size_t)(bm0 + rep * 64 + srow) * K + k0 + half * 32 + scol],
                      &As[half * 4096 + rep * 2048 + tid * 8]);
            gld16(&B[(size_t)(bn0 + srow) * K + k0 + half * 32 + scol],
                  &Bs[half * 2048 + tid * 8]);
        }
        __syncthreads();
#pragma unroll
        for (int kk = 0; kk < 2; ++kk) {
            f16x8 af[2], bf[4];
#pragma unroll
            for (int i = 0; i < 2; ++i) af[i] = *(const f16x8*)&As[kk * 4096 + (wid * 32 + i * 16 + l16) * 32 + quad * 8];
#pragma unroll
            for (int j = 0; j < 4; ++j) bf[j] = *(const f16x8*)&Bs[kk * 2048 + (j * 16 + l16) * 32 + quad * 8];
#pragma unroll
            for (int i = 0; i < 2; ++i)
#pragma unroll
                for (int j = 0; j < 4; ++j)
                    acc[i][j] = __builtin_amdgcn_mfma_f32_16x16x32_f16(af[i], bf[j], acc[i][j], 0, 0, 0);
        }
    }

#pragma unroll
    for (int j = 0; j < 4; ++j) {
        int n = bn0 + j * 16 + l16;
        float bv = bias[n];
#pragma unroll
        for (int i = 0; i < 2; ++i) {
            int m0 = bm0 + wid * 32 + i * 16 + quad * 4;
#pragma unroll
            for (int r = 0; r < 4; ++r)
                OutF[(size_t)(m0 + r) * N + n] = acc[i][j][r] + bv;
        }
    }
}

// ---------------- windowed flash attention: S^T form, log2 softmax, analytic pads,
// double-buffered staging; 256 thr = 4 waves x 32 q-rows (mt=2) -> half the LDS reads/q ----------------
__global__ __launch_bounds__(256, 4) void attn_win(const u16* __restrict__ QK, const u16* __restrict__ VT,
                                                   u16* __restrict__ AO) {
    const int qt = blockIdx.x, w = blockIdx.y, h = blockIdx.z;
    const int tid = threadIdx.x, wid = tid >> 6, lid = tid & 63, quad = lid >> 4, l16 = lid & 15;

    __shared__ __align__(16) u16 Ks[2][2 * 64 * 32];   // [buf][d-half][key][d32]
    __shared__ __align__(16) u16 Vt[2][2 * 64 * 36];   // [buf][key-half][d][key32+pad4]

    // Q frags (B-operand), pre-scaled by log2(e); 2 m-tiles of 16 q-rows
    const int qrow0 = w * WSZ + qt * 128 + wid * 32;
    const _Float16 L2E = (_Float16)1.44269504f;
    f16x8 qf[2][2];
#pragma unroll
    for (int mt = 0; mt < 2; ++mt)
#pragma unroll
        for (int ks = 0; ks < 2; ++ks) {
            qf[mt][ks] = *(const f16x8*)&QK[(size_t)(qrow0 + mt * 16 + l16) * 2048 + h * 64 + ks * 32 + quad * 8];
#pragma unroll
            for (int j = 0; j < 8; ++j) qf[mt][ks][j] *= L2E;
        }

    // pad-key closed form: all pad keys score -sum_d(q_d) (log2-scaled), v = -1
    const int npad = (w == 0 || w == 7) ? 512 : 0;
    float s_p[2] = {0.f, 0.f};
    if (npad) {
#pragma unroll
        for (int mt = 0; mt < 2; ++mt) {
            float sq = 0.f;
#pragma unroll
            for (int j = 0; j < 8; ++j) sq += (float)qf[mt][0][j] + (float)qf[mt][1][j];
            sq += __shfl_xor(sq, 16, 64);
            sq += __shfl_xor(sq, 32, 64);
            s_p[mt] = -sq;
        }
    }

    f32x4 oacc[2][4] = {};
    float mrun[2] = {-30000.f, -30000.f};
    float lsum[2] = {0.f, 0.f};

    const int g0base = (w - 1) * WSZ;
    const int rqloc = qt * 128 + wid * 32 + l16;   // + mt*16
    const int rqw0 = qt * 128 + wid * 32;          // wave-uniform min q (span 32)

    // contiguous chunk range: band [2qt, 2qt+17] ∩ real [(1-w)*8, 71-8w] ∩ [0,23]
    int cfirst = 2 * qt; if ((1 - w) * 8 > cfirst) cfirst = (1 - w) * 8;
    int clast = 2 * qt + 17; if (71 - 8 * w < clast) clast = 71 - 8 * w; if (clast > 23) clast = 23;

    // staging maps (256 thr): K: key = tid>>2, col8 = (tid&3)*8, two d-halves;
    // V: d = tid>>2, 16 keys starting (tid&3)*16
    const size_t kgoff = 1024 + h * 64 + (tid & 3) * 8 + (size_t)(tid >> 2) * 2048;
    const int kl = tid * 8;
    const int vd = tid >> 2, vk0 = (tid & 3) * 16;
    const u16* vgrow = VT + (size_t)(h * 64 + vd) * 4096 + vk0;
    const int vloff = (vk0 >> 5) * 2304 + vd * 36 + (vk0 & 31);

    // stage first chunk into buf 0
    {
        const int g0 = g0base + cfirst * 64;
        uint4 va = *(const uint4*)(vgrow + g0);
        uint4 vb = *(const uint4*)(vgrow + g0 + 8);
        gld16(QK + (size_t)g0 * 2048 + kgoff, &Ks[0][0] + kl);
        gld16(QK + (size_t)g0 * 2048 + kgoff + 32, &Ks[0][0] + 2048 + kl);
        u16* vp = &Vt[0][0] + vloff;
        *(uint2*)(vp)      = make_uint2(va.x, va.y);
        *(uint2*)(vp + 4)  = make_uint2(va.z, va.w);
        *(uint2*)(vp + 8)  = make_uint2(vb.x, vb.y);
        *(uint2*)(vp + 12) = make_uint2(vb.z, vb.w);
    }

    int ib = 0;
    for (int c = cfirst; c <= clast; ++c, ib ^= 1) {
        __syncthreads();   // stage(c -> ib) complete

        const bool has_next = (c < clast);
        uint4 vna, vnb;
        if (has_next) {
            const int gn = g0base + (c + 1) * 64;
            vna = *(const uint4*)(vgrow + gn);                              // VGPR prefetch
            vnb = *(const uint4*)(vgrow + gn + 8);
            gld16(QK + (size_t)gn * 2048 + kgoff, &Ks[ib ^ 1][0] + kl);     // async K -> other buf
            gld16(QK + (size_t)gn * 2048 + kgoff + 32, &Ks[ib ^ 1][0] + 2048 + kl);
        }

        const u16* KsB = &Ks[ib][0];
        const u16* VtB = &Vt[ib][0];

        // S^T = K * Q^T : lane holds S^T[key=nt*16+quad*4+r][q=l16]; kf read ONCE for both mt
        f32x4 sc[2][4];
#pragma unroll
        for (int nt = 0; nt < 4; ++nt) {
            f16x8 kf0 = *(const f16x8*)&KsB[(nt * 16 + l16) * 32 + quad * 8];
            f16x8 kf1 = *(const f16x8*)&KsB[2048 + (nt * 16 + l16) * 32 + quad * 8];
#pragma unroll
            for (int mt = 0; mt < 2; ++mt) {
                f32x4 t = {};
                t = __builtin_amdgcn_mfma_f32_16x16x32_f16(kf0, qf[mt][0], t, 0, 0, 0);
                t = __builtin_amdgcn_mfma_f32_16x16x32_f16(kf1, qf[mt][1], t, 0, 0, 0);
                sc[mt][nt] = t;
            }
        }

        // mask only when the wave's 32-row band edge intersects the chunk (wave-uniform)
        const bool needs_mask = (c * 64 < rqw0 + 32) || (c * 64 + 63 > rqw0 + 1024);
        if (needs_mask) {
#pragma unroll
            for (int mt = 0; mt < 2; ++mt) {
                const int rq = rqloc + mt * 16;
#pragma unroll
                for (int nt = 0; nt < 4; ++nt)
#pragma unroll
                    for (int r = 0; r < 4; ++r) {
                        int n = c * 64 + nt * 16 + quad * 4 + r;
                        if (n < rq || n > rq + 1024) sc[mt][nt][r] = -30000.f;
                    }
            }
        }

        // online softmax (log2 domain) per m-tile, conditional rescale
        f16x4 pf[2][4];
#pragma unroll
        for (int mt = 0; mt < 2; ++mt) {
            float mloc = mrun[mt];
#pragma unroll
            for (int nt = 0; nt < 4; ++nt)
                mloc = fmaxf(mloc, fmaxf(fmaxf(sc[mt][nt][0], sc[mt][nt][1]), fmaxf(sc[mt][nt][2], sc[mt][nt][3])));
            mloc = fmaxf(mloc, __shfl_xor(mloc, 16, 64));
            mloc = fmaxf(mloc, __shfl_xor(mloc, 32, 64));

            const bool up = __any(mloc > mrun[mt]);
            float ls = 0.f;
#pragma unroll
            for (int nt = 0; nt < 4; ++nt)
#pragma unroll
                for (int r = 0; r < 4; ++r) {
                    float p = exp2f(sc[mt][nt][r] - mloc);
                    ls += p;
                    pf[mt][nt][r] = (_Float16)p;
                }
            if (up) {
                float alpha = exp2f(mrun[mt] - mloc);
                mrun[mt] = mloc;
                lsum[mt] = lsum[mt] * alpha + ls;
                float ao[4];
#pragma unroll
                for (int r = 0; r < 4; ++r) ao[r] = __shfl(alpha, quad * 4 + r, 64);
#pragma unroll
                for (int dt = 0; dt < 4; ++dt)
#pragma unroll
                    for (int r = 0; r < 4; ++r) oacc[mt][dt][r] *= ao[r];
            } else {
                lsum[mt] += ls;
            }
        }

        // O += P V ; vf read ONCE for both mt
#pragma unroll
        for (int nt = 0; nt < 4; ++nt)
#pragma unroll
            for (int dt = 0; dt < 4; ++dt) {
                f16x4 vf = *(const f16x4*)&VtB[(nt >> 1) * 2304 + (dt * 16 + l16) * 36 + (nt & 1) * 16 + quad * 4];
                oacc[0][dt] = __builtin_amdgcn_mfma_f32_16x16x16f16(pf[0][nt], vf, oacc[0][dt], 0, 0, 0);
                oacc[1][dt] = __builtin_amdgcn_mfma_f32_16x16x16f16(pf[1][nt], vf, oacc[1][dt], 0, 0, 0);
            }

        // park prefetched V into the other buffer
        if (has_next) {
            u16* vp = &Vt[ib ^ 1][0] + vloff;
            *(uint2*)(vp)      = make_uint2(vna.x, vna.y);
            *(uint2*)(vp + 4)  = make_uint2(vna.z, vna.w);
            *(uint2*)(vp + 8)  = make_uint2(vnb.x, vnb.y);
            *(uint2*)(vp + 12) = make_uint2(vnb.z, vnb.w);
        }
    }

    // epilogue per m-tile: reduce l, fold pads, normalize, store f16
#pragma unroll
    for (int mt = 0; mt < 2; ++mt) {
        float lt = lsum[mt];
        lt += __shfl_xor(lt, 16, 64);
        lt += __shfl_xor(lt, 32, 64);
        float aW = 1.f, pw = 0.f;
        if (npad) {
            float mnew = fmaxf(mrun[mt], s_p[mt]);
            aW = exp2f(mrun[mt] - mnew);
            pw = 512.f * exp2f(s_p[mt] - mnew);
            lt = lt * aW + pw;
        }
        float linv = 1.f / lt;
        float lrec[4], arow[4], pwrow[4];
#pragma unroll
        for (int r = 0; r < 4; ++r) {
            lrec[r]  = __shfl(linv, quad * 4 + r, 64);
            arow[r]  = __shfl(aW,   quad * 4 + r, 64);
            pwrow[r] = __shfl(pw,   quad * 4 + r, 64);
        }
#pragma unroll
        for (int dt = 0; dt < 4; ++dt)
#pragma unroll
            for (int r = 0; r < 4; ++r) {
                int srow = qrow0 + mt * 16 + quad * 4 + r;
                int col = h * 64 + dt * 16 + l16;
                float o = (oacc[mt][dt][r] * arow[r] - pwrow[r]) * lrec[r];   // pad v = -1 every dim
                AO[(size_t)srow * E + col] = f2h_bits(o);
            }
    }
}

// ---------------- launch ----------------
extern "C" void kernel_launch(void* const* d_in, const int* in_sizes, int n_in,
                              void* d_out, int out_size, void* d_ws, size_t ws_size,
                              hipStream_t stream) {
    const float* x  = (const float*)d_in[0];
    const float* wq = (const float*)d_in[1];
    const float* bq = (const float*)d_in[2];
    const float* wk = (const float*)d_in[3];
    const float* bk = (const float*)d_in[4];
    const float* wv = (const float*)d_in[5];
    const float* bv = (const float*)d_in[6];
    const float* wo = (const float*)d_in[7];
    const float* bo = (const float*)d_in[8];
    float* out = (float*)d_out;

    char* ws = (char*)d_ws;
    u16* XH  = (u16*)(ws);               // 4096x1024 f16   [0, 8388608)
    u16* WC  = (u16*)(ws + 8388608);     // 3072x1024 f16   [8388608, 14680064)
    u16* WOh = (u16*)(ws + 14680064);    // 1024x1024 f16   [14680064, 16777216)
    u16* QK  = (u16*)(ws + 16777216);    // 4096x2048 f16   [16777216, 33554432)
    u16* VTg = (u16*)(ws + 33554432);    // 1024x4096 f16   [33554432, 41943040)
    u16* AOh = (u16*)(ws + 41943040);    // 4096x1024 f16   [41943040, 50331648)

    CvtArgs ca;
    ca.s[0] = x;  ca.d[0] = XH;            ca.n[0] = 4194304;
    ca.s[1] = wq; ca.d[1] = WC;            ca.n[1] = 1048576;
    ca.s[2] = wk; ca.d[2] = WC + 1048576;  ca.n[2] = 1048576;
    ca.s[3] = wv; ca.d[3] = WC + 2097152;  ca.n[3] = 1048576;
    ca.s[4] = wo; ca.d[4] = WOh;           ca.n[4] = 1048576;
    cvt5<<<dim3(1024, 5), 256, 0, stream>>>(ca);

    gemm_qkv<<<dim3(32, 24), 256, 0, stream>>>(XH, WC, QK, VTg, bq, bk, bv, 1024);
    attn_win<<<dim3(4, 8, 16), 256, 0, stream>>>(QK, VTg, AOh);
    gemm_n64<<<dim3(32, 16), 256, 0, stream>>>(AOh, WOh, out, bo, 1024, 1024);
}

// Round 9
// 188.914 us; speedup vs baseline: 1.0971x; 1.0971x over previous
//
#include <hip/hip_runtime.h>
#include <stdint.h>

#define S 4096
#define E 1024
#define NH 16
#define HD 64
#define WSZ 512

typedef _Float16 f16x8 __attribute__((ext_vector_type(8)));
typedef _Float16 f16x4 __attribute__((ext_vector_type(4)));
typedef float f32x4 __attribute__((ext_vector_type(4)));
typedef unsigned short u16;
typedef unsigned int u32;

__device__ __forceinline__ u16 f2h_bits(float f) {
    union { _Float16 h; u16 u; } cv; cv.h = (_Float16)f; return cv.u;
}

__device__ __forceinline__ void gld16(const u16* g, u16* l) {
    __builtin_amdgcn_global_load_lds((const __attribute__((address_space(1))) void*)g,
                                     (__attribute__((address_space(3))) void*)l, 16, 0, 0);
}

// ---------------- fused fp32->fp16 converts (5 segments, 1 launch) ----------------
struct CvtArgs {
    const float* s[5];
    u16* d[5];
    int n[5];
};
__global__ void cvt5(CvtArgs a) {
    int seg = blockIdx.y;
    const float* __restrict__ s = a.s[seg];
    u16* __restrict__ d = a.d[seg];
    int n = a.n[seg];
    for (int i = (blockIdx.x * 256 + threadIdx.x) * 4; i < n; i += gridDim.x * 1024) {
        float4 f = *(const float4*)&s[i];
        uint2 o;
        o.x = (u32)f2h_bits(f.x) | ((u32)f2h_bits(f.y) << 16);
        o.y = (u32)f2h_bits(f.z) | ((u32)f2h_bits(f.w) << 16);
        *(uint2*)&d[i] = o;
    }
}

// ---------------- QKV bt-GEMM: 128x128 tile, BK=64 (split-half LDS, 64B row stride).
// n<2048 -> f16 QK (stride 2048); n>=2048 -> V^T f16 OutVT[n-2048][4096]. ----------------
__global__ __launch_bounds__(256) void gemm_qkv(
    const u16* __restrict__ A, const u16* __restrict__ B,
    u16* __restrict__ OutQK, u16* __restrict__ OutVT,
    const float* __restrict__ b0, const float* __restrict__ b1, const float* __restrict__ b2,
    int K) {
    __shared__ __align__(16) u16 As[2 * 128 * 32];   // [khalf][row][32]
    __shared__ __align__(16) u16 Bs[2 * 128 * 32];
    const int tid = threadIdx.x;
    const int wid = tid >> 6, lid = tid & 63, quad = lid >> 4, l16 = lid & 15;
    const int wm = wid >> 1, wn = wid & 1;
    const int bm0 = blockIdx.x * 128, bn0 = blockIdx.y * 128;

    f32x4 acc[4][4] = {};
    const int srow = tid >> 2, scol = (tid & 3) * 8;   // lane-linear LDS dest per call

    for (int k0 = 0; k0 < K; k0 += 64) {
        __syncthreads();
#pragma unroll
        for (int half = 0; half < 2; ++half)
#pragma unroll
            for (int rep = 0; rep < 2; ++rep) {
                gld16(&A[(size_t)(bm0 + rep * 64 + srow) * K + k0 + half * 32 + scol],
                      &As[half * 4096 + rep * 2048 + tid * 8]);
                gld16(&B[(size_t)(bn0 + rep * 64 + srow) * K + k0 + half * 32 + scol],
                      &Bs[half * 4096 + rep * 2048 + tid * 8]);
            }
        __syncthreads();
#pragma unroll
        for (int kk = 0; kk < 2; ++kk) {
            f16x8 af[4], bf[4];
#pragma unroll
            for (int i = 0; i < 4; ++i) af[i] = *(const f16x8*)&As[kk * 4096 + (wm * 64 + i * 16 + l16) * 32 + quad * 8];
#pragma unroll
            for (int j = 0; j < 4; ++j) bf[j] = *(const f16x8*)&Bs[kk * 4096 + (wn * 64 + j * 16 + l16) * 32 + quad * 8];
#pragma unroll
            for (int i = 0; i < 4; ++i)
#pragma unroll
                for (int j = 0; j < 4; ++j)
                    acc[i][j] = __builtin_amdgcn_mfma_f32_16x16x32_f16(af[i], bf[j], acc[i][j], 0, 0, 0);
        }
    }

    const bool isV = (bn0 >= 2048);   // block-uniform
#pragma unroll
    for (int j = 0; j < 4; ++j) {
        int n = bn0 + wn * 64 + j * 16 + l16;
        float bias = (n < 1024) ? b0[n] : (n < 2048 ? b1[n - 1024] : b2[n - 2048]);
#pragma unroll
        for (int i = 0; i < 4; ++i) {
            int m0 = bm0 + wm * 64 + i * 16 + quad * 4;
            if (!isV) {
#pragma unroll
                for (int r = 0; r < 4; ++r)
                    OutQK[(size_t)(m0 + r) * 2048 + n] = f2h_bits(acc[i][j][r] + bias);
            } else {
                u16 h0 = f2h_bits(acc[i][j][0] + bias);
                u16 h1 = f2h_bits(acc[i][j][1] + bias);
                u16 h2 = f2h_bits(acc[i][j][2] + bias);
                u16 h3 = f2h_bits(acc[i][j][3] + bias);
                uint2 pk;
                pk.x = (u32)h0 | ((u32)h1 << 16);
                pk.y = (u32)h2 | ((u32)h3 << 16);
                *(uint2*)&OutVT[(size_t)(n - 2048) * 4096 + m0] = pk;
            }
        }
    }
}

// ---------------- final proj bt-GEMM: 128(M)x64(N) tile, BK=64, f32 out + bias ----------------
__global__ __launch_bounds__(256) void gemm_n64(
    const u16* __restrict__ A, const u16* __restrict__ B, float* __restrict__ OutF,
    const float* __restrict__ bias, int N, int K) {
    __shared__ __align__(16) u16 As[2 * 128 * 32];
    __shared__ __align__(16) u16 Bs[2 * 64 * 32];
    const int tid = threadIdx.x;
    const int wid = tid >> 6, lid = tid & 63, quad = lid >> 4, l16 = lid & 15;
    const int bm0 = blockIdx.x * 128, bn0 = blockIdx.y * 64;

    f32x4 acc[2][4] = {};
    const int srow = tid >> 2, scol = (tid & 3) * 8;

    for (int k0 = 0; k0 < K; k0 += 64) {
        __syncthreads();
#pragma unroll
        for (int half = 0; half < 2; ++half) {
#pragma unroll
            for (int rep = 0; rep < 2; ++rep)
                gld16(&A[(size_t)(bm0 + rep * 64 + srow) * K + k0 + half * 32 + scol],
                      &As[half * 4096 + rep * 2048 + tid * 8]);
            gld16(&B[(size_t)(bn0 + srow) * K + k0 + half * 32 + scol],
                  &Bs[half * 2048 + tid * 8]);
        }
        __syncthreads();
#pragma unroll
        for (int kk = 0; kk < 2; ++kk) {
            f16x8 af[2], bf[4];
#pragma unroll
            for (int i = 0; i < 2; ++i) af[i] = *(const f16x8*)&As[kk * 4096 + (wid * 32 + i * 16 + l16) * 32 + quad * 8];
#pragma unroll
            for (int j = 0; j < 4; ++j) bf[j] = *(const f16x8*)&Bs[kk * 2048 + (j * 16 + l16) * 32 + quad * 8];
#pragma unroll
            for (int i = 0; i < 2; ++i)
#pragma unroll
                for (int j = 0; j < 4; ++j)
                    acc[i][j] = __builtin_amdgcn_mfma_f32_16x16x32_f16(af[i], bf[j], acc[i][j], 0, 0, 0);
        }
    }

#pragma unroll
    for (int j = 0; j < 4; ++j) {
        int n = bn0 + j * 16 + l16;
        float bv = bias[n];
#pragma unroll
        for (int i = 0; i < 2; ++i) {
            int m0 = bm0 + wid * 32 + i * 16 + quad * 4;
#pragma unroll
            for (int r = 0; r < 4; ++r)
                OutF[(size_t)(m0 + r) * N + n] = acc[i][j][r] + bv;
        }
    }
}

// ---------------- windowed flash attention: S^T form, log2 softmax, analytic pads,
// 128-key double-buffered slabs (2 sub-chunks per barrier -> 9 drains vs 17),
// 512 thr = 8 waves x 16 q-rows, grid (4,8,16) -> 16 waves/CU ----------------
__global__ __launch_bounds__(512, 2) void attn_win(const u16* __restrict__ QK, const u16* __restrict__ VT,
                                                   u16* __restrict__ AO) {
    const int qt = blockIdx.x, w = blockIdx.y, h = blockIdx.z;
    const int tid = threadIdx.x, wid = tid >> 6, lid = tid & 63, quad = lid >> 4, l16 = lid & 15;

    __shared__ __align__(16) u16 Ks[2][2 * 128 * 32];   // [buf][d-half][key(128)][d32] 16KB/buf
    __shared__ __align__(16) u16 Vt[2][4 * 64 * 36];    // [buf][key-grp(4x32)][d][key32+pad4] 18KB/buf

    // Q frags (B-operand), pre-scaled by log2(e)
    const int qrow = w * WSZ + qt * 128 + wid * 16 + l16;
    const _Float16 L2E = (_Float16)1.44269504f;
    f16x8 qf[2];
#pragma unroll
    for (int ks = 0; ks < 2; ++ks) {
        qf[ks] = *(const f16x8*)&QK[(size_t)qrow * 2048 + h * 64 + ks * 32 + quad * 8];
#pragma unroll
        for (int j = 0; j < 8; ++j) qf[ks][j] *= L2E;
    }

    // pad-key closed form: all pad keys score -sum_d(q_d) (log2-scaled), v = -1
    const int npad = (w == 0 || w == 7) ? 512 : 0;
    float s_p = 0.f;
    if (npad) {
        float sq = 0.f;
#pragma unroll
        for (int j = 0; j < 8; ++j) sq += (float)qf[0][j] + (float)qf[1][j];
        sq += __shfl_xor(sq, 16, 64);
        sq += __shfl_xor(sq, 32, 64);
        s_p = -sq;
    }

    f32x4 oacc[4] = {};
    float mrun = -30000.f;
    float lsum = 0.f;

    const int g0base = (w - 1) * WSZ;
    const int rqloc = qt * 128 + wid * 16 + l16;
    const int rqw0 = qt * 128 + wid * 16;

    // contiguous chunk range: band [2qt, 2qt+17] ∩ real [(1-w)*8, 71-8w] ∩ [0,23]
    int cfirst = 2 * qt; if ((1 - w) * 8 > cfirst) cfirst = (1 - w) * 8;
    int clast = 2 * qt + 17; if (71 - 8 * w < clast) clast = 71 - 8 * w; if (clast > 23) clast = 23;

    // staging maps (512 thr, 128-key slab):
    // K: key = tid>>2 (0..127), d = half*32 + (tid&3)*8  -> lane-linear LDS dest
    // V: d = tid>>3 (0..63), 16 keys from (tid&7)*16
    const int krow = tid >> 2;
    const size_t kg = 1024 + h * 64 + (tid & 3) * 8;
    const int kl = tid * 8;
    const int vd = tid >> 3, vk0 = (tid & 7) * 16;
    const u16* vgrow = VT + (size_t)(h * 64 + vd) * 4096;
    const int vloff = (vk0 >> 5) * 2304 + vd * 36 + (vk0 & 31);
    // NOTE: tail slabs may stage rows past the band end; addresses stay inside the
    // workspace (QK/VTg/AOh are contiguous) and the data is never read by compute.

    // stage first slab into buf 0
    {
        const int g0 = g0base + cfirst * 64;
        uint4 va = *(const uint4*)(vgrow + g0 + vk0);
        uint4 vb = *(const uint4*)(vgrow + g0 + vk0 + 8);
        gld16(QK + (size_t)(g0 + krow) * 2048 + kg,      &Ks[0][kl]);
        gld16(QK + (size_t)(g0 + krow) * 2048 + kg + 32, &Ks[0][4096 + kl]);
        u16* vp = &Vt[0][vloff];
        *(uint2*)(vp)      = make_uint2(va.x, va.y);
        *(uint2*)(vp + 4)  = make_uint2(va.z, va.w);
        *(uint2*)(vp + 8)  = make_uint2(vb.x, vb.y);
        *(uint2*)(vp + 12) = make_uint2(vb.z, vb.w);
    }

    int ib = 0;
    for (int c0 = cfirst; c0 <= clast; c0 += 2, ib ^= 1) {
        __syncthreads();   // slab(c0 -> ib) staged; prior compute on ib^1 done

        const bool has_next = (c0 + 2 <= clast);
        uint4 vna, vnb;
        if (has_next) {
            const int gn = g0base + (c0 + 2) * 64;
            vna = *(const uint4*)(vgrow + gn + vk0);                         // VGPR prefetch
            vnb = *(const uint4*)(vgrow + gn + vk0 + 8);
            gld16(QK + (size_t)(gn + krow) * 2048 + kg,      &Ks[ib ^ 1][kl]);   // async K
            gld16(QK + (size_t)(gn + krow) * 2048 + kg + 32, &Ks[ib ^ 1][4096 + kl]);
        }

        const u16* KsB = &Ks[ib][0];
        const u16* VtB = &Vt[ib][0];
        const int ncs = (c0 + 1 <= clast) ? 2 : 1;

#pragma unroll
        for (int cs = 0; cs < 2; ++cs) {
            if (cs >= ncs) break;
            const int c = c0 + cs;

            // S^T = K * Q^T : lane holds S^T[key=nt*16+quad*4+r][q=l16]  (log2-scaled)
            f32x4 sc[4];
#pragma unroll
            for (int nt = 0; nt < 4; ++nt) {
                f16x8 kf0 = *(const f16x8*)&KsB[(cs * 64 + nt * 16 + l16) * 32 + quad * 8];
                f16x8 kf1 = *(const f16x8*)&KsB[4096 + (cs * 64 + nt * 16 + l16) * 32 + quad * 8];
                f32x4 t = {};
                t = __builtin_amdgcn_mfma_f32_16x16x32_f16(kf0, qf[0], t, 0, 0, 0);
                t = __builtin_amdgcn_mfma_f32_16x16x32_f16(kf1, qf[1], t, 0, 0, 0);
                sc[nt] = t;
            }

            // mask only when this wave's band edge intersects the chunk (wave-uniform)
            const bool needs_mask = (c * 64 < rqw0 + 16) || (c * 64 + 63 > rqw0 + 1024);
            if (needs_mask) {
#pragma unroll
                for (int nt = 0; nt < 4; ++nt)
#pragma unroll
                    for (int r = 0; r < 4; ++r) {
                        int n = c * 64 + nt * 16 + quad * 4 + r;
                        if (n < rqloc || n > rqloc + 1024) sc[nt][r] = -30000.f;
                    }
            }

            // online softmax (log2 domain), conditional rescale
            float mloc = mrun;
#pragma unroll
            for (int nt = 0; nt < 4; ++nt)
                mloc = fmaxf(mloc, fmaxf(fmaxf(sc[nt][0], sc[nt][1]), fmaxf(sc[nt][2], sc[nt][3])));
            mloc = fmaxf(mloc, __shfl_xor(mloc, 16, 64));
            mloc = fmaxf(mloc, __shfl_xor(mloc, 32, 64));

            const bool up = __any(mloc > mrun);
            float ls = 0.f;
            f16x4 pf[4];
#pragma unroll
            for (int nt = 0; nt < 4; ++nt)
#pragma unroll
                for (int r = 0; r < 4; ++r) {
                    float p = exp2f(sc[nt][r] - mloc);
                    ls += p;
                    pf[nt][r] = (_Float16)p;
                }
            if (up) {
                float alpha = exp2f(mrun - mloc);
                mrun = mloc;
                lsum = lsum * alpha + ls;
                float ao[4];
#pragma unroll
                for (int r = 0; r < 4; ++r) ao[r] = __shfl(alpha, quad * 4 + r, 64);
#pragma unroll
                for (int dt = 0; dt < 4; ++dt)
#pragma unroll
                    for (int r = 0; r < 4; ++r) oacc[dt][r] *= ao[r];
            } else {
                lsum += ls;
            }

            // O += P V  (P direct from regs as A-operand of 16x16x16)
#pragma unroll
            for (int nt = 0; nt < 4; ++nt)
#pragma unroll
                for (int dt = 0; dt < 4; ++dt) {
                    f16x4 vf = *(const f16x4*)&VtB[(cs * 2 + (nt >> 1)) * 2304 + (dt * 16 + l16) * 36 + (nt & 1) * 16 + quad * 4];
                    oacc[dt] = __builtin_amdgcn_mfma_f32_16x16x16f16(pf[nt], vf, oacc[dt], 0, 0, 0);
                }
        }

        // park prefetched V into the other buffer
        if (has_next) {
            u16* vp = &Vt[ib ^ 1][vloff];
            *(uint2*)(vp)      = make_uint2(vna.x, vna.y);
            *(uint2*)(vp + 4)  = make_uint2(vna.z, vna.w);
            *(uint2*)(vp + 8)  = make_uint2(vnb.x, vnb.y);
            *(uint2*)(vp + 12) = make_uint2(vnb.z, vnb.w);
        }
    }

    // epilogue: reduce l across quads, fold pad contribution, normalize, store f16
    float lt = lsum;
    lt += __shfl_xor(lt, 16, 64);
    lt += __shfl_xor(lt, 32, 64);
    float aW = 1.f, pw = 0.f;
    if (npad) {
        float mnew = fmaxf(mrun, s_p);
        aW = exp2f(mrun - mnew);
        pw = 512.f * exp2f(s_p - mnew);
        lt = lt * aW + pw;
    }
    float linv = 1.f / lt;
    float lrec[4], arow[4], pwrow[4];
#pragma unroll
    for (int r = 0; r < 4; ++r) {
        lrec[r]  = __shfl(linv, quad * 4 + r, 64);
        arow[r]  = __shfl(aW,   quad * 4 + r, 64);
        pwrow[r] = __shfl(pw,   quad * 4 + r, 64);
    }
#pragma unroll
    for (int dt = 0; dt < 4; ++dt)
#pragma unroll
        for (int r = 0; r < 4; ++r) {
            int srow = w * WSZ + qt * 128 + wid * 16 + quad * 4 + r;
            int col = h * 64 + dt * 16 + l16;
            float o = (oacc[dt][r] * arow[r] - pwrow[r]) * lrec[r];   // pad v = -1 every dim
            AO[(size_t)srow * E + col] = f2h_bits(o);
        }
}

// ---------------- launch ----------------
extern "C" void kernel_launch(void* const* d_in, const int* in_sizes, int n_in,
                              void* d_out, int out_size, void* d_ws, size_t ws_size,
                              hipStream_t stream) {
    const float* x  = (const float*)d_in[0];
    const float* wq = (const float*)d_in[1];
    const float* bq = (const float*)d_in[2];
    const float* wk = (const float*)d_in[3];
    const float* bk = (const float*)d_in[4];
    const float* wv = (const float*)d_in[5];
    const float* bv = (const float*)d_in[6];
    const float* wo = (const float*)d_in[7];
    const float* bo = (const float*)d_in[8];
    float* out = (float*)d_out;

    char* ws = (char*)d_ws;
    u16* XH  = (u16*)(ws);               // 4096x1024 f16   [0, 8388608)
    u16* WC  = (u16*)(ws + 8388608);     // 3072x1024 f16   [8388608, 14680064)
    u16* WOh = (u16*)(ws + 14680064);    // 1024x1024 f16   [14680064, 16777216)
    u16* QK  = (u16*)(ws + 16777216);    // 4096x2048 f16   [16777216, 33554432)
    u16* VTg = (u16*)(ws + 33554432);    // 1024x4096 f16   [33554432, 41943040)
    u16* AOh = (u16*)(ws + 41943040);    // 4096x1024 f16   [41943040, 50331648)

    CvtArgs ca;
    ca.s[0] = x;  ca.d[0] = XH;            ca.n[0] = 4194304;
    ca.s[1] = wq; ca.d[1] = WC;            ca.n[1] = 1048576;
    ca.s[2] = wk; ca.d[2] = WC + 1048576;  ca.n[2] = 1048576;
    ca.s[3] = wv; ca.d[3] = WC + 2097152;  ca.n[3] = 1048576;
    ca.s[4] = wo; ca.d[4] = WOh;           ca.n[4] = 1048576;
    cvt5<<<dim3(1024, 5), 256, 0, stream>>>(ca);

    gemm_qkv<<<dim3(32, 24), 256, 0, stream>>>(XH, WC, QK, VTg, bq, bk, bv, 1024);
    attn_win<<<dim3(4, 8, 16), 512, 0, stream>>>(QK, VTg, AOh);
    gemm_n64<<<dim3(32, 16), 256, 0, stream>>>(AOh, WOh, out, bo, 1024, 1024);
}